// Round 8
// baseline (940.087 us; speedup 1.0000x reference)
//
#include <hip/hip_runtime.h>
#include <hip/hip_bf16.h>

#define T_DIM 512
#define H_DIM 4096
#define F_DIM 14336
#define KSEG  8   // split-K segments for down GEMM (14336/8 = 1792 = 28 x 64)

typedef __attribute__((ext_vector_type(8))) short bf16x8;
typedef __attribute__((ext_vector_type(4))) float f32x4;

// 1-op f32->bf16 (v_cvt, RNE in HW). Confirmed R5/R6: VALUBusy 25 -> 19.
__device__ __forceinline__ unsigned short f2bf(float f) {
    union { __hip_bfloat16 h; unsigned short u; } cv;
    cv.h = __float2bfloat16(f);
    return cv.u;
}

// dequant 4 int-quant values with (scale, zero) -> 4 bf16 -> 8B LDS store
__device__ __forceinline__ void dq16(int4 qv, float s, float z, unsigned short* dst) {
    float nzs = -z * s;
    ushort4 o;
    o.x = f2bf(fmaf((float)qv.x, s, nzs));
    o.y = f2bf(fmaf((float)qv.y, s, nzs));
    o.z = f2bf(fmaf((float)qv.z, s, nzs));
    o.w = f2bf(fmaf((float)qv.w, s, nzs));
    *(ushort4*)dst = o;
}

// async global->LDS, 16B per lane. LDS dest = wave-uniform base + lane*16
// (HW constraint m104); swizzle achieved by pre-swizzling the per-lane
// GLOBAL address (m173 pattern).
__device__ __forceinline__ void gload16(const void* g, void* l) {
    __builtin_amdgcn_global_load_lds(
        (const __attribute__((address_space(1))) void*)(unsigned long long)(uintptr_t)g,
        (__attribute__((address_space(3))) void*)(uintptr_t)l, 16, 0, 0);
}

// Zero d_out (harness poisons with 0xAA; down_kernel accumulates via atomics).
__global__ __launch_bounds__(256) void zero_out(float4* __restrict__ out) {
    out[blockIdx.x * 256 + threadIdx.x] = make_float4(0.f, 0.f, 0.f, 0.f);
}

// X fp32 -> bf16 once.
__global__ __launch_bounds__(256) void cvt_x(const float* __restrict__ X,
                                             unsigned short* __restrict__ Xb) {
    int i = (blockIdx.x * 256 + threadIdx.x) * 4;
    float4 v = *(const float4*)&X[i];
    ushort4 o;
    o.x = f2bf(v.x); o.y = f2bf(v.y); o.z = f2bf(v.z); o.w = f2bf(v.w);
    *(ushort4*)&Xb[i] = o;
}

// ---------------------------------------------------------------------------
// G = silu(X@W1^T) * (X@W3^T) -> bf16 [T,F]
// Tile M128 x N64 x K64(=GROUP). 4 waves: wave&1 = m-half, wave>>1 = matrix.
// SCHEDULE (the R7 post-mortem fix): per iteration
//   [top]  issue pW(it+1) HBM loads FIRST, then 4 global_load_lds X(it+1)
//   MFMA(buf it)                       <- pW/X latency hides under this
//   dequant pW(it+1) -> buf(it+1)      <- waits pW with ~MFMA-phase in flight
//   __syncthreads()                    <- drains X gloads (L2, long covered)
// Previous rounds issued pW immediately BEFORE the barrier -> ~0-cycle
// issue->use window -> a full unhidden HBM round trip per K-step. That was
// the real bottleneck (R7: removing a barrier was neutral).
// X via global_load_lds: linear LDS [128][64], chunk c of row r stored at
// slot c^(r&7) by pre-swizzling the per-lane SOURCE column; MFMA read
// applies the same XOR -> 2-way bank conflicts (free).
// REGISTER CLIFF (R2/R3/R5): acc 64 + pW 32 at (256,2) only. DO NOT raise
// min-waves; DO NOT add cross-phase register arrays.
// LDS: 2 x (16384 X + 2*9216 W) = 69632 B -> 2 blocks/CU.
// Grid: flat 896, XCD-swizzled.
// ---------------------------------------------------------------------------
__global__ __launch_bounds__(256, 2)
void gate_up_kernel(const unsigned short* __restrict__ Xb,
                    const int* __restrict__ W1q, const float* __restrict__ sc1,
                    const float* __restrict__ zp1,
                    const int* __restrict__ W3q, const float* __restrict__ sc3,
                    const float* __restrict__ zp3,
                    unsigned short* __restrict__ G)
{
    constexpr int LK = 72;                 // W rows: 144 B stride (+4 banks/row)
    constexpr int XB = 128 * 64 * 2;       // 16384 B linear X tile
    constexpr int WB = 64 * LK * 2;        // 9216 B per W matrix
    constexpr int BUFB = XB + 2 * WB;      // 34816 B per buffer
    __shared__ __align__(16) char smem[2 * BUFB];   // 69632 B
    float* sEx = (float*)smem;  // epilogue reuse of buf0: 128*65*4 = 33280 B

    const int t = threadIdx.x, wave = t >> 6, lane = t & 63;
    const int r = lane & 15, q = lane >> 4;
    const int mh  = (wave & 1) * 64;   // wave's m-offset in tile
    const int mat = wave >> 1;         // 0 -> W1, 1 -> W3
    const int rs  = r & 7;             // row swizzle key for X reads

    const int b = blockIdx.x;
    const int xcd = b & 7, lb = b >> 3;         // lb in [0,112)
    const int m0 = (lb & 3) * 128;
    const int n0 = (xcd * 28 + (lb >> 2)) * 64; // n-tile in [0,224)
    const int SG = H_DIM / 64;

    const int wrow = t >> 4, wc = (t & 15) * 4;   // W: rows wrow+16i, 4 int32

    // per-lane pre-swizzled X source: row m0+wave*32+j*8+lrow, chunk lc
    const int lrow = lane >> 3;                   // 0..7 within 8-row group
    const int lc   = (lane & 7) ^ lrow;           // swizzled chunk 0..7
    const unsigned short* xsrc =
        Xb + (size_t)(m0 + wave * 32 + lrow) * H_DIM + lc * 8;

    // weight-only prefetch (32 VGPRs)
    int4 pW1[4], pW3[4];

    // ---- prologue: pW(0) sync, X(0) gload -> buf0, dequant(0) -> buf0 ----
    {
        #pragma unroll
        for (int i = 0; i < 4; ++i) {
            size_t off = (size_t)(n0 + wrow + 16 * i) * H_DIM + wc;
            pW1[i] = *(const int4*)&W1q[off];
            pW3[i] = *(const int4*)&W3q[off];
        }
        #pragma unroll
        for (int j = 0; j < 4; ++j)
            gload16(xsrc + (size_t)j * 8 * H_DIM, smem + (wave * 4 + j) * 1024);
        unsigned short* sW1 = (unsigned short*)(smem + XB);
        unsigned short* sW3 = (unsigned short*)(smem + XB + WB);
        #pragma unroll
        for (int i = 0; i < 4; ++i) {
            int row = wrow + 16 * i;
            int sidx = (n0 + row) * SG;   // gidx 0
            dq16(pW1[i], sc1[sidx], zp1[sidx], &sW1[row * LK + wc]);
            dq16(pW3[i], sc3[sidx], zp3[sidx], &sW3[row * LK + wc]);
        }
    }
    __syncthreads();

    f32x4 acc[4][4];
    #pragma unroll
    for (int a = 0; a < 4; ++a)
        #pragma unroll
        for (int c = 0; c < 4; ++c) acc[a][c] = (f32x4){0.f, 0.f, 0.f, 0.f};

    constexpr int NIT = H_DIM / 64;   // 64
    #pragma unroll 2
    for (int it = 0; it < NIT; ++it) {
        const char* cb = smem + (it & 1) * BUFB;
        char* nb = smem + ((it + 1) & 1) * BUFB;
        const int kn = (it + 1) * 64;

        // ---- issue next tile's loads: pW FIRST (HBM, FIFO-first so the
        // dequant wait leaves X outstanding), then X gloads ----
        if (it + 1 < NIT) {
            #pragma unroll
            for (int i = 0; i < 4; ++i) {
                size_t off = (size_t)(n0 + wrow + 16 * i) * H_DIM + kn + wc;
                pW1[i] = *(const int4*)&W1q[off];
                pW3[i] = *(const int4*)&W3q[off];
            }
            #pragma unroll
            for (int j = 0; j < 4; ++j)
                gload16(xsrc + (size_t)j * 8 * H_DIM + kn,
                        nb + (wave * 4 + j) * 1024);
        }

        // ---- MFMA phase: tile `it` (covers the in-flight loads) ----
        const unsigned short* sX = (const unsigned short*)cb;
        const unsigned short* sB = (const unsigned short*)(cb + XB + mat * WB);
        #pragma unroll
        for (int kh = 0; kh < 2; ++kh) {
            const int kb = kh * 32 + q * 8;            // W column offset
            const int xc = (kh * 4 + q) ^ rs;          // swizzled X chunk
            bf16x8 av[4], bv[4];
            #pragma unroll
            for (int im = 0; im < 4; ++im)
                av[im] = *(const bf16x8*)&sX[(mh + im * 16 + r) * 64 + xc * 8];
            #pragma unroll
            for (int j = 0; j < 4; ++j)
                bv[j] = *(const bf16x8*)&sB[(j * 16 + r) * LK + kb];
            #pragma unroll
            for (int im = 0; im < 4; ++im)
                #pragma unroll
                for (int j = 0; j < 4; ++j)
                    acc[im][j] = __builtin_amdgcn_mfma_f32_16x16x32_bf16(av[im], bv[j], acc[im][j], 0, 0, 0);
        }

        // ---- dequant pW(it+1) -> buf(it+1); barrier drains X gloads ----
        if (it + 1 < NIT) {
            unsigned short* nW1 = (unsigned short*)(nb + XB);
            unsigned short* nW3 = (unsigned short*)(nb + XB + WB);
            const int gidx = it + 1;
            #pragma unroll
            for (int i = 0; i < 4; ++i) {
                int row = wrow + 16 * i;
                int sidx = (n0 + row) * SG + gidx;
                dq16(pW1[i], sc1[sidx], zp1[sidx], &nW1[row * LK + wc]);
                dq16(pW3[i], sc3[sidx], zp3[sidx], &nW3[row * LK + wc]);
            }
            __syncthreads();
        }
    }

    // ---- epilogue: exchange g3 via LDS (buf0 region; final MFMA read buf1,
    // disjoint), then silu(g1)*g3 ----
    if (mat == 1) {
        #pragma unroll
        for (int im = 0; im < 4; ++im)
            #pragma unroll
            for (int j = 0; j < 4; ++j)
                #pragma unroll
                for (int reg = 0; reg < 4; ++reg)
                    sEx[(mh + im * 16 + q * 4 + reg) * 65 + j * 16 + r] = acc[im][j][reg];
    }
    __syncthreads();
    if (mat == 0) {
        #pragma unroll
        for (int im = 0; im < 4; ++im)
            #pragma unroll
            for (int j = 0; j < 4; ++j)
                #pragma unroll
                for (int reg = 0; reg < 4; ++reg) {
                    int ml = mh + im * 16 + q * 4 + reg;
                    int nl = j * 16 + r;
                    float g1 = acc[im][j][reg];
                    float g3 = sEx[ml * 65 + nl];
                    float val = g1 / (1.f + __expf(-g1)) * g3;
                    G[(size_t)(m0 + ml) * F_DIM + n0 + nl] = f2bf(val);
                }
    }
}

// ---------------------------------------------------------------------------
// out += G @ W2^T (split-K, fp32 atomics). Tile M128 x N128 x K64, 4 waves
// x 64x64. Same early-issue + gload_lds(A) schedule as gate_up.
// LDS: 2 x (16384 A + 18432 W) = 69632 B. Grid: flat 1024, XCD-swizzled.
// ---------------------------------------------------------------------------
__global__ __launch_bounds__(256, 2)
void down_kernel(const unsigned short* __restrict__ G,
                 const int* __restrict__ W2q, const float* __restrict__ sc2,
                 const float* __restrict__ zp2,
                 float* __restrict__ Out)
{
    constexpr int LK = 72;
    constexpr int AB = 128 * 64 * 2;       // 16384 B linear A tile
    constexpr int WB = 128 * LK * 2;       // 18432 B
    constexpr int BUFB = AB + WB;          // 34816 B
    __shared__ __align__(16) char smem[2 * BUFB];   // 69632 B

    const int t = threadIdx.x, wave = t >> 6, lane = t & 63;
    const int r = lane & 15, q = lane >> 4;
    const int wm = (wave & 1) * 64, wn = (wave >> 1) * 64;
    const int rs = r & 7;

    const int b = blockIdx.x;
    const int xcd = b & 7, lb = b >> 3;          // lb in [0,128)
    const int m0 = (lb & 3) * 128;
    const int pair = xcd * 32 + (lb >> 2);       // [0,256)
    const int n0 = (pair >> 3) * 128;            // 32 n-tiles
    const int kbeg = (pair & 7) * (F_DIM / KSEG);
    const int SG = F_DIM / 64;

    const int wrow = t >> 4, wc = (t & 15) * 4;

    const int lrow = lane >> 3;
    const int lc   = (lane & 7) ^ lrow;
    const unsigned short* asrc =
        G + (size_t)(m0 + wave * 32 + lrow) * F_DIM + kbeg + lc * 8;

    // weight-only prefetch (32 VGPRs)
    int4 pW[8];

    // ---- prologue ----
    {
        #pragma unroll
        for (int i = 0; i < 8; ++i)
            pW[i] = *(const int4*)&W2q[(size_t)(n0 + wrow + 16 * i) * F_DIM + kbeg + wc];
        #pragma unroll
        for (int j = 0; j < 4; ++j)
            gload16(asrc + (size_t)j * 8 * F_DIM, smem + (wave * 4 + j) * 1024);
        unsigned short* sW = (unsigned short*)(smem + AB);
        const int gidx = kbeg >> 6;
        #pragma unroll
        for (int i = 0; i < 8; ++i) {
            int row = wrow + 16 * i;
            int sidx = (n0 + row) * SG + gidx;
            dq16(pW[i], sc2[sidx], zp2[sidx], &sW[row * LK + wc]);
        }
    }
    __syncthreads();

    f32x4 acc[4][4];
    #pragma unroll
    for (int a = 0; a < 4; ++a)
        #pragma unroll
        for (int c = 0; c < 4; ++c) acc[a][c] = (f32x4){0.f, 0.f, 0.f, 0.f};

    constexpr int NIT = (F_DIM / KSEG) / 64;   // 28
    #pragma unroll 2
    for (int it = 0; it < NIT; ++it) {
        const char* cb = smem + (it & 1) * BUFB;
        char* nb = smem + ((it + 1) & 1) * BUFB;
        const int kn = kbeg + (it + 1) * 64;

        if (it + 1 < NIT) {
            #pragma unroll
            for (int i = 0; i < 8; ++i)
                pW[i] = *(const int4*)&W2q[(size_t)(n0 + wrow + 16 * i) * F_DIM + kn + wc];
            #pragma unroll
            for (int j = 0; j < 4; ++j)
                gload16(asrc + (size_t)j * 8 * F_DIM + (it + 1) * 64,
                        nb + (wave * 4 + j) * 1024);
        }

        const unsigned short* sA = (const unsigned short*)cb;
        const unsigned short* sW = (const unsigned short*)(cb + AB);
        #pragma unroll
        for (int kh = 0; kh < 2; ++kh) {
            const int kb = kh * 32 + q * 8;
            const int xc = (kh * 4 + q) ^ rs;
            bf16x8 av[4], bv[4];
            #pragma unroll
            for (int im = 0; im < 4; ++im)
                av[im] = *(const bf16x8*)&sA[(wm + im * 16 + r) * 64 + xc * 8];
            #pragma unroll
            for (int j = 0; j < 4; ++j)
                bv[j] = *(const bf16x8*)&sW[(wn + j * 16 + r) * LK + kb];
            #pragma unroll
            for (int im = 0; im < 4; ++im)
                #pragma unroll
                for (int j = 0; j < 4; ++j)
                    acc[im][j] = __builtin_amdgcn_mfma_f32_16x16x32_bf16(av[im], bv[j], acc[im][j], 0, 0, 0);
        }

        if (it + 1 < NIT) {
            unsigned short* nW = (unsigned short*)(nb + AB);
            const int gidx = kn >> 6;
            #pragma unroll
            for (int i = 0; i < 8; ++i) {
                int row = wrow + 16 * i;
                int sidx = (n0 + row) * SG + gidx;
                dq16(pW[i], sc2[sidx], zp2[sidx], &nW[row * LK + wc]);
            }
            __syncthreads();
        }
    }

    #pragma unroll
    for (int im = 0; im < 4; ++im)
        #pragma unroll
        for (int j = 0; j < 4; ++j)
            #pragma unroll
            for (int reg = 0; reg < 4; ++reg) {
                int m = m0 + wm + im * 16 + q * 4 + reg;
                int h = n0 + wn + j * 16 + r;
                atomicAdd(&Out[(size_t)m * H_DIM + h], acc[im][j][reg]);
            }
}

extern "C" void kernel_launch(void* const* d_in, const int* in_sizes, int n_in,
                              void* d_out, int out_size, void* d_ws, size_t ws_size,
                              hipStream_t stream) {
    const float* X   = (const float*)d_in[0];
    const int*   W1q = (const int*)d_in[1];
    const float* s1  = (const float*)d_in[2];
    const float* z1  = (const float*)d_in[3];
    const int*   W3q = (const int*)d_in[4];
    const float* s3  = (const float*)d_in[5];
    const float* z3  = (const float*)d_in[6];
    const int*   W2q = (const int*)d_in[7];
    const float* s2  = (const float*)d_in[8];
    const float* z2  = (const float*)d_in[9];
    float* Out = (float*)d_out;

    unsigned short* Xb = (unsigned short*)d_ws;                       // 4 MB
    unsigned short* G  = (unsigned short*)((char*)d_ws + (4 << 20));  // 14.7 MB

    zero_out<<<2048, 256, 0, stream>>>((float4*)Out);
    cvt_x<<<2048, 256, 0, stream>>>(X, Xb);
    gate_up_kernel<<<896, 256, 0, stream>>>(Xb, W1q, s1, z1, W3q, s3, z3, G);
    down_kernel<<<1024, 256, 0, stream>>>(G, W2q, s2, z2, Out);
}

// Round 9
// 858.667 us; speedup vs baseline: 1.0948x; 1.0948x over previous
//
#include <hip/hip_runtime.h>
#include <hip/hip_bf16.h>

#define T_DIM 512
#define H_DIM 4096
#define F_DIM 14336
#define KSEG  4   // split-K segments for down GEMM (14336/4 = 3584 = 56 x 64)

typedef __attribute__((ext_vector_type(8))) short bf16x8;
typedef __attribute__((ext_vector_type(4))) float f32x4;

// 1-op f32->bf16 (v_cvt, RNE in HW). Confirmed R5/R6: VALUBusy 25 -> 19.
__device__ __forceinline__ unsigned short f2bf(float f) {
    union { __hip_bfloat16 h; unsigned short u; } cv;
    cv.h = __float2bfloat16(f);
    return cv.u;
}

// dequant 4 int-quant values with (scale, zero) -> 4 bf16 -> 8B LDS store
__device__ __forceinline__ void dq16(int4 qv, float s, float z, unsigned short* dst) {
    float nzs = -z * s;
    ushort4 o;
    o.x = f2bf(fmaf((float)qv.x, s, nzs));
    o.y = f2bf(fmaf((float)qv.y, s, nzs));
    o.z = f2bf(fmaf((float)qv.z, s, nzs));
    o.w = f2bf(fmaf((float)qv.w, s, nzs));
    *(ushort4*)dst = o;
}

// X fp32 -> bf16 once.
__global__ __launch_bounds__(256) void cvt_x(const float* __restrict__ X,
                                             unsigned short* __restrict__ Xb) {
    int i = (blockIdx.x * 256 + threadIdx.x) * 4;
    float4 v = *(const float4*)&X[i];
    ushort4 o;
    o.x = f2bf(v.x); o.y = f2bf(v.y); o.z = f2bf(v.z); o.w = f2bf(v.w);
    *(ushort4*)&Xb[i] = o;
}

// Out = sum of KSEG partial buffers (replaces 16.7M colliding atomicAdds —
// the R8 post-mortem finding: the atomic epilogue was ~370us of down's
// ~530us). Writes EVERY output element -> also replaces zero_out (poison
// overwritten).
__global__ __launch_bounds__(256) void reduce_out(const float4* __restrict__ P,
                                                  float4* __restrict__ out) {
    constexpr size_t S = (size_t)T_DIM * H_DIM / 4;
    size_t i = (size_t)blockIdx.x * 256 + threadIdx.x;   // over 524288 float4
    float4 a = P[i], b = P[i + S], c = P[i + 2 * S], d = P[i + 3 * S];
    out[i] = make_float4(a.x + b.x + c.x + d.x, a.y + b.y + c.y + d.y,
                         a.z + b.z + c.z + d.z, a.w + b.w + c.w + d.w);
}

// ---------------------------------------------------------------------------
// G = silu(X@W1^T) * (X@W3^T) -> bf16 [T,F]  — EXACT R7 kernel (315us, best
// measured). Tile M128 x N64 x K64. 4 waves: wave&1 = m-half, wave>>1 = matrix.
// Double-buffered LDS, one barrier per K-step. Weight-only register prefetch.
// REGISTER CLIFF (R2/R3/R5/R8): acc 64 + pW 32 at (256,2), pW issued LATE
// (after dequant) so it is NOT live across the MFMA phase. R8 proved issuing
// pW before MFMA costs +24 VGPR and -13% perf. DO NOT raise min-waves bound;
// DO NOT extend register live ranges across the MFMA phase.
// Grid: flat 896, XCD-swizzled (4 m-siblings per XCD share W panels in L2).
// ---------------------------------------------------------------------------
__global__ __launch_bounds__(256, 2)
void gate_up_kernel(const unsigned short* __restrict__ Xb,
                    const int* __restrict__ W1q, const float* __restrict__ sc1,
                    const float* __restrict__ zp1,
                    const int* __restrict__ W3q, const float* __restrict__ sc3,
                    const float* __restrict__ zp3,
                    unsigned short* __restrict__ G)
{
    constexpr int LK = 72;  // 144 B row stride, 16B-aligned, +4 bank shift/row
    constexpr int BUFB = (128 + 64 + 64) * LK * 2;   // 36864 B per buffer
    __shared__ __align__(16) char smem[2 * BUFB];    // 73728 B
    float* sEx = (float*)smem;  // epilogue reuse of buf0: 128*65*4 = 33280 B

    const int t = threadIdx.x, wave = t >> 6, lane = t & 63;
    const int r = lane & 15, q = lane >> 4;
    const int mh  = (wave & 1) * 64;   // wave's m-offset in tile
    const int mat = wave >> 1;         // 0 -> W1, 1 -> W3

    const int b = blockIdx.x;
    const int xcd = b & 7, lb = b >> 3;         // lb in [0,112)
    const int m0 = (lb & 3) * 128;
    const int n0 = (xcd * 28 + (lb >> 2)) * 64; // n-tile in [0,224)
    const int SG = H_DIM / 64;

    const int xrow = t >> 3, xch = (t & 7) * 8;   // X: rows xrow+32i, 16B chunk
    const int wrow = t >> 4, wc = (t & 15) * 4;   // W: rows wrow+16i, 4 int32

    // weight-only prefetch (32 VGPRs live across barriers)
    int4 pW1[4], pW3[4];
    #pragma unroll
    for (int i = 0; i < 4; ++i) {
        size_t off = (size_t)(n0 + wrow + 16 * i) * H_DIM + wc;
        pW1[i] = *(const int4*)&W1q[off];
        pW3[i] = *(const int4*)&W3q[off];
    }

    // ---- prologue: stage tile 0 into buf0, then issue W(tile 1) ----
    {
        unsigned short* sX  = (unsigned short*)smem;
        unsigned short* sW1 = (unsigned short*)(smem + 128 * LK * 2);
        unsigned short* sW3 = (unsigned short*)(smem + 192 * LK * 2);
        #pragma unroll
        for (int i = 0; i < 4; ++i) {
            int4 xv = *(const int4*)&Xb[(size_t)(m0 + xrow + 32 * i) * H_DIM + xch];
            *(int4*)&sX[(xrow + 32 * i) * LK + xch] = xv;
        }
        #pragma unroll
        for (int i = 0; i < 4; ++i) {
            int row = wrow + 16 * i;
            int sidx = (n0 + row) * SG;   // gidx 0
            dq16(pW1[i], sc1[sidx], zp1[sidx], &sW1[row * LK + wc]);
            dq16(pW3[i], sc3[sidx], zp3[sidx], &sW3[row * LK + wc]);
        }
        #pragma unroll
        for (int i = 0; i < 4; ++i) {
            size_t off = (size_t)(n0 + wrow + 16 * i) * H_DIM + 64 + wc;
            pW1[i] = *(const int4*)&W1q[off];
            pW3[i] = *(const int4*)&W3q[off];
        }
    }
    __syncthreads();

    f32x4 acc[4][4];
    #pragma unroll
    for (int a = 0; a < 4; ++a)
        #pragma unroll
        for (int c = 0; c < 4; ++c) acc[a][c] = (f32x4){0.f, 0.f, 0.f, 0.f};

    constexpr int NIT = H_DIM / 64;   // 64
    #pragma unroll 2
    for (int it = 0; it < NIT; ++it) {
        const char* cb = smem + (it & 1) * BUFB;
        const unsigned short* sX = (const unsigned short*)cb;
        const unsigned short* sB =
            (const unsigned short*)(cb + (mat ? 192 : 128) * LK * 2);

        // ---- MFMA phase: tile `it` (staged last iter; no entry wait) ----
        #pragma unroll
        for (int kh = 0; kh < 2; ++kh) {
            const int kb = kh * 32 + q * 8;
            bf16x8 av[4], bv[4];
            #pragma unroll
            for (int im = 0; im < 4; ++im)
                av[im] = *(const bf16x8*)&sX[(mh + im * 16 + r) * LK + kb];
            #pragma unroll
            for (int j = 0; j < 4; ++j)
                bv[j] = *(const bf16x8*)&sB[(j * 16 + r) * LK + kb];
            #pragma unroll
            for (int im = 0; im < 4; ++im)
                #pragma unroll
                for (int j = 0; j < 4; ++j)
                    acc[im][j] = __builtin_amdgcn_mfma_f32_16x16x32_bf16(av[im], bv[j], acc[im][j], 0, 0, 0);
        }

        // ---- stage tile it+1 into the other buffer ----
        if (it < NIT - 1) {
            char* nb = smem + ((it + 1) & 1) * BUFB;
            unsigned short* nX  = (unsigned short*)nb;
            unsigned short* nW1 = (unsigned short*)(nb + 128 * LK * 2);
            unsigned short* nW3 = (unsigned short*)(nb + 192 * LK * 2);
            const int kn = (it + 1) * 64;
            #pragma unroll
            for (int i = 0; i < 4; ++i) {
                int4 xv = *(const int4*)&Xb[(size_t)(m0 + xrow + 32 * i) * H_DIM + kn + xch];
                *(int4*)&nX[(xrow + 32 * i) * LK + xch] = xv;
            }
            const int gidx = it + 1;
            #pragma unroll
            for (int i = 0; i < 4; ++i) {
                int row = wrow + 16 * i;
                int sidx = (n0 + row) * SG + gidx;
                dq16(pW1[i], sc1[sidx], zp1[sidx], &nW1[row * LK + wc]);
                dq16(pW3[i], sc3[sidx], zp3[sidx], &nW3[row * LK + wc]);
            }
            if (it < NIT - 2) {
                const int kf = (it + 2) * 64;
                #pragma unroll
                for (int i = 0; i < 4; ++i) {
                    size_t off = (size_t)(n0 + wrow + 16 * i) * H_DIM + kf + wc;
                    pW1[i] = *(const int4*)&W1q[off];
                    pW3[i] = *(const int4*)&W3q[off];
                }
            }
            __syncthreads();
        }
    }

    // ---- epilogue: exchange g3 via LDS (buf0 region; final MFMA read buf1,
    // disjoint), then silu(g1)*g3 ----
    if (mat == 1) {
        #pragma unroll
        for (int im = 0; im < 4; ++im)
            #pragma unroll
            for (int j = 0; j < 4; ++j)
                #pragma unroll
                for (int reg = 0; reg < 4; ++reg)
                    sEx[(mh + im * 16 + q * 4 + reg) * 65 + j * 16 + r] = acc[im][j][reg];
    }
    __syncthreads();
    if (mat == 0) {
        #pragma unroll
        for (int im = 0; im < 4; ++im)
            #pragma unroll
            for (int j = 0; j < 4; ++j)
                #pragma unroll
                for (int reg = 0; reg < 4; ++reg) {
                    int ml = mh + im * 16 + q * 4 + reg;
                    int nl = j * 16 + r;
                    float g1 = acc[im][j][reg];
                    float g3 = sEx[ml * 65 + nl];
                    float val = g1 / (1.f + __expf(-g1)) * g3;
                    G[(size_t)(m0 + ml) * F_DIM + n0 + nl] = f2bf(val);
                }
    }
}

// ---------------------------------------------------------------------------
// Parts[ks] = G @ W2^T over k-segment ks (NO atomics — plain stores to a
// per-segment fp32 buffer; reduce_out sums the 4 segments). Tile M128 x N128
// x K64, 4 waves x 64x64, R7-style double-buffer single-barrier loop.
// KSEG 8 -> 4: grid 512 = exactly 2 blocks/CU, one co-resident round, NIT=56.
// Grid: flat 512 = 4(m) x 32(n) x 4(kseg), XCD-swizzled (m-siblings share
// the W2 panel in their XCD's L2).
// ---------------------------------------------------------------------------
__global__ __launch_bounds__(256, 2)
void down_kernel(const unsigned short* __restrict__ G,
                 const int* __restrict__ W2q, const float* __restrict__ sc2,
                 const float* __restrict__ zp2,
                 float* __restrict__ Parts)
{
    constexpr int LK = 72;
    constexpr int BUFB = (128 + 128) * LK * 2;       // 36864 B per buffer
    __shared__ __align__(16) char smem[2 * BUFB];    // 73728 B

    const int t = threadIdx.x, wave = t >> 6, lane = t & 63;
    const int r = lane & 15, q = lane >> 4;
    const int wm = (wave & 1) * 64, wn = (wave >> 1) * 64;

    const int b = blockIdx.x;
    const int xcd = b & 7, lb = b >> 3;          // lb in [0,64)
    const int m0 = (lb & 3) * 128;
    const int pair = xcd * 16 + (lb >> 2);       // [0,128)
    const int n0 = (pair >> 2) * 128;            // 32 n-tiles
    const int ks = pair & 3;                     // k-segment
    const int kbeg = ks * (F_DIM / KSEG);
    const int SG = F_DIM / 64;

    const int arow = t >> 3, ach = (t & 7) * 8;
    const int wrow = t >> 4, wc = (t & 15) * 4;

    // weight-only prefetch (32 VGPRs)
    int4 pW[8];
    #pragma unroll
    for (int i = 0; i < 8; ++i)
        pW[i] = *(const int4*)&W2q[(size_t)(n0 + wrow + 16 * i) * F_DIM + kbeg + wc];

    // ---- prologue: stage tile 0 into buf0, then issue W(tile 1) ----
    {
        unsigned short* sA = (unsigned short*)smem;
        unsigned short* sW = (unsigned short*)(smem + 128 * LK * 2);
        #pragma unroll
        for (int i = 0; i < 4; ++i) {
            int4 gv = *(const int4*)&G[(size_t)(m0 + arow + 32 * i) * F_DIM + kbeg + ach];
            *(int4*)&sA[(arow + 32 * i) * LK + ach] = gv;
        }
        const int gidx = kbeg >> 6;
        #pragma unroll
        for (int i = 0; i < 8; ++i) {
            int row = wrow + 16 * i;
            int sidx = (n0 + row) * SG + gidx;
            dq16(pW[i], sc2[sidx], zp2[sidx], &sW[row * LK + wc]);
        }
        #pragma unroll
        for (int i = 0; i < 8; ++i)
            pW[i] = *(const int4*)&W2q[(size_t)(n0 + wrow + 16 * i) * F_DIM + kbeg + 64 + wc];
    }
    __syncthreads();

    f32x4 acc[4][4];
    #pragma unroll
    for (int a = 0; a < 4; ++a)
        #pragma unroll
        for (int c = 0; c < 4; ++c) acc[a][c] = (f32x4){0.f, 0.f, 0.f, 0.f};

    constexpr int NIT = (F_DIM / KSEG) / 64;   // 56
    #pragma unroll 2
    for (int it = 0; it < NIT; ++it) {
        const char* cb = smem + (it & 1) * BUFB;
        const unsigned short* sA = (const unsigned short*)cb;
        const unsigned short* sW = (const unsigned short*)(cb + 128 * LK * 2);

        // ---- MFMA phase: tile `it` ----
        #pragma unroll
        for (int kh = 0; kh < 2; ++kh) {
            const int kb = kh * 32 + q * 8;
            bf16x8 av[4], bv[4];
            #pragma unroll
            for (int im = 0; im < 4; ++im)
                av[im] = *(const bf16x8*)&sA[(wm + im * 16 + r) * LK + kb];
            #pragma unroll
            for (int j = 0; j < 4; ++j)
                bv[j] = *(const bf16x8*)&sW[(wn + j * 16 + r) * LK + kb];
            #pragma unroll
            for (int im = 0; im < 4; ++im)
                #pragma unroll
                for (int j = 0; j < 4; ++j)
                    acc[im][j] = __builtin_amdgcn_mfma_f32_16x16x32_bf16(av[im], bv[j], acc[im][j], 0, 0, 0);
        }

        // ---- stage tile it+1 ----
        if (it < NIT - 1) {
            char* nb = smem + ((it + 1) & 1) * BUFB;
            unsigned short* nA = (unsigned short*)nb;
            unsigned short* nW = (unsigned short*)(nb + 128 * LK * 2);
            const int kn = kbeg + (it + 1) * 64;
            #pragma unroll
            for (int i = 0; i < 4; ++i) {
                int4 gv = *(const int4*)&G[(size_t)(m0 + arow + 32 * i) * F_DIM + kn + ach];
                *(int4*)&nA[(arow + 32 * i) * LK + ach] = gv;
            }
            const int gidx = kn >> 6;
            #pragma unroll
            for (int i = 0; i < 8; ++i) {
                int row = wrow + 16 * i;
                int sidx = (n0 + row) * SG + gidx;
                dq16(pW[i], sc2[sidx], zp2[sidx], &nW[row * LK + wc]);
            }
            if (it < NIT - 2) {
                const int kf = kbeg + (it + 2) * 64;
                #pragma unroll
                for (int i = 0; i < 8; ++i)
                    pW[i] = *(const int4*)&W2q[(size_t)(n0 + wrow + 16 * i) * F_DIM + kf + wc];
            }
            __syncthreads();
        }
    }

    // ---- epilogue: plain stores to this segment's partial buffer ----
    float* P = Parts + (size_t)ks * T_DIM * H_DIM;
    #pragma unroll
    for (int im = 0; im < 4; ++im)
        #pragma unroll
        for (int j = 0; j < 4; ++j)
            #pragma unroll
            for (int reg = 0; reg < 4; ++reg) {
                int m = m0 + wm + im * 16 + q * 4 + reg;
                int h = n0 + wn + j * 16 + r;
                P[(size_t)m * H_DIM + h] = acc[im][j][reg];
            }
}

extern "C" void kernel_launch(void* const* d_in, const int* in_sizes, int n_in,
                              void* d_out, int out_size, void* d_ws, size_t ws_size,
                              hipStream_t stream) {
    const float* X   = (const float*)d_in[0];
    const int*   W1q = (const int*)d_in[1];
    const float* s1  = (const float*)d_in[2];
    const float* z1  = (const float*)d_in[3];
    const int*   W3q = (const int*)d_in[4];
    const float* s3  = (const float*)d_in[5];
    const float* z3  = (const float*)d_in[6];
    const int*   W2q = (const int*)d_in[7];
    const float* s2  = (const float*)d_in[8];
    const float* z2  = (const float*)d_in[9];
    float* Out = (float*)d_out;

    unsigned short* Xb = (unsigned short*)d_ws;                        // 4 MB
    unsigned short* G  = (unsigned short*)((char*)d_ws + (4 << 20));   // 14.7 MB
    float* Parts       = (float*)((char*)d_ws + (20 << 20));           // 32 MB (4 x 8 MB)

    cvt_x<<<2048, 256, 0, stream>>>(X, Xb);
    gate_up_kernel<<<896, 256, 0, stream>>>(Xb, W1q, s1, z1, W3q, s3, z3, G);
    down_kernel<<<512, 256, 0, stream>>>(G, W2q, s2, z2, Parts);
    reduce_out<<<2048, 256, 0, stream>>>((const float4*)Parts, (float4*)Out);
}

// Round 10
// 834.949 us; speedup vs baseline: 1.1259x; 1.0284x over previous
//
#include <hip/hip_runtime.h>
#include <hip/hip_bf16.h>

#define T_DIM 512
#define H_DIM 4096
#define F_DIM 14336
#define KSEG  4   // split-K segments for down GEMM (14336/4 = 3584 = 56 x 64)

typedef __attribute__((ext_vector_type(8))) short bf16x8;
typedef __attribute__((ext_vector_type(4))) float f32x4;

// 1-op f32->bf16 (v_cvt, RNE in HW). Confirmed R5/R6: VALUBusy 25 -> 19.
__device__ __forceinline__ unsigned short f2bf(float f) {
    union { __hip_bfloat16 h; unsigned short u; } cv;
    cv.h = __float2bfloat16(f);
    return cv.u;
}

// dequant 4 int-quant values with (scale, zero) -> 4 bf16 -> 8B LDS store
__device__ __forceinline__ void dq16(int4 qv, float s, float z, unsigned short* dst) {
    float nzs = -z * s;
    ushort4 o;
    o.x = f2bf(fmaf((float)qv.x, s, nzs));
    o.y = f2bf(fmaf((float)qv.y, s, nzs));
    o.z = f2bf(fmaf((float)qv.z, s, nzs));
    o.w = f2bf(fmaf((float)qv.w, s, nzs));
    *(ushort4*)dst = o;
}

// async global->LDS, 16B per lane. LDS dest = wave-uniform base + lane*16
// (HW constraint m104); swizzle via pre-swizzled per-lane GLOBAL address.
__device__ __forceinline__ void gload16(const void* g, void* l) {
    __builtin_amdgcn_global_load_lds(
        (const __attribute__((address_space(1))) void*)(unsigned long long)(uintptr_t)g,
        (__attribute__((address_space(3))) void*)(uintptr_t)l, 16, 0, 0);
}

// X fp32 -> bf16 once.
__global__ __launch_bounds__(256) void cvt_x(const float* __restrict__ X,
                                             unsigned short* __restrict__ Xb) {
    int i = (blockIdx.x * 256 + threadIdx.x) * 4;
    float4 v = *(const float4*)&X[i];
    ushort4 o;
    o.x = f2bf(v.x); o.y = f2bf(v.y); o.z = f2bf(v.z); o.w = f2bf(v.w);
    *(ushort4*)&Xb[i] = o;
}

// Out = sum of KSEG partial buffers. Writes every output -> replaces zero_out.
__global__ __launch_bounds__(256) void reduce_out(const float4* __restrict__ P,
                                                  float4* __restrict__ out) {
    constexpr size_t S = (size_t)T_DIM * H_DIM / 4;
    size_t i = (size_t)blockIdx.x * 256 + threadIdx.x;
    float4 a = P[i], b = P[i + S], c = P[i + 2 * S], d = P[i + 3 * S];
    out[i] = make_float4(a.x + b.x + c.x + d.x, a.y + b.y + c.y + d.y,
                         a.z + b.z + c.z + d.z, a.w + b.w + c.w + d.w);
}

// ---------------------------------------------------------------------------
// G = silu(X@W1^T) * (X@W3^T) -> bf16 [T,F]. Tile M128 x N64 x K64.
// 4 waves: wave&1 = m-half, wave>>1 = matrix.
// R10 SCHEDULE: X tile via global_load_lds (async DMA, zero VGPR), issued at
// the TOP of iteration J for tile J+1 into the just-freed buffer; consumed
// only after the end-of-J barrier (vmcnt drain = sync). X L3-latency (~600cy
// serial per K-step at 2 waves/SIMD — the R9 post-mortem stall) now hides
// under MFMA + dequant. pW issue stays LATE (R7 form — R8 proved early-issue
// pW costs +24 VGPR and -13%). Scales stay sync (they overlap the pW wait).
// X LDS layout: linear [128][64], chunk c of row R holds cols (c^(R&7))*8
// via pre-swizzled per-lane source column (R8-proven correct); MFMA read
// applies the same XOR -> conflict-free.
// REGISTER CLIFF (R2/R3/R5/R8): acc 64 + pW 32 at (256,2) ONLY. DO NOT raise
// min-waves; DO NOT extend reg live ranges across the MFMA phase.
// LDS: 2 x (16384 X + 2*9216 W) = 69632 B -> 2 blocks/CU.
// Grid: flat 896, XCD-swizzled (4 m-siblings per XCD share W panels in L2).
// ---------------------------------------------------------------------------
__global__ __launch_bounds__(256, 2)
void gate_up_kernel(const unsigned short* __restrict__ Xb,
                    const int* __restrict__ W1q, const float* __restrict__ sc1,
                    const float* __restrict__ zp1,
                    const int* __restrict__ W3q, const float* __restrict__ sc3,
                    const float* __restrict__ zp3,
                    unsigned short* __restrict__ G)
{
    constexpr int LK = 72;                 // W rows: 144 B stride
    constexpr int XB = 128 * 64 * 2;       // 16384 B linear X tile
    constexpr int WB = 64 * LK * 2;        // 9216 B per W matrix
    constexpr int BUFB = XB + 2 * WB;      // 34816 B per buffer
    __shared__ __align__(16) char smem[2 * BUFB];   // 69632 B
    float* sEx = (float*)smem;  // epilogue reuse of buf0 (final MFMA reads buf1)

    const int t = threadIdx.x, wave = t >> 6, lane = t & 63;
    const int r = lane & 15, q = lane >> 4;
    const int mh  = (wave & 1) * 64;
    const int mat = wave >> 1;
    const int rs  = r & 7;             // X read swizzle key

    const int b = blockIdx.x;
    const int xcd = b & 7, lb = b >> 3;         // lb in [0,112)
    const int m0 = (lb & 3) * 128;
    const int n0 = (xcd * 28 + (lb >> 2)) * 64; // n-tile in [0,224)
    const int SG = H_DIM / 64;

    const int wrow = t >> 4, wc = (t & 15) * 4;   // W: rows wrow+16i, 4 int32

    // per-lane pre-swizzled X source (R8-proven)
    const int lrow = lane >> 3;                   // 0..7
    const int lc   = (lane & 7) ^ lrow;           // swizzled chunk
    const unsigned short* xsrc =
        Xb + (size_t)(m0 + wave * 32 + lrow) * H_DIM + lc * 8;

    // weight-only prefetch (32 VGPRs live across barriers)
    int4 pW1[4], pW3[4];

    // ---- prologue: issue X(0) DMA first, pW(0) sync, dequant(0), pW(1) ----
    {
        #pragma unroll
        for (int j = 0; j < 4; ++j)
            gload16(xsrc + (size_t)j * 8 * H_DIM, smem + (wave * 4 + j) * 1024);
        #pragma unroll
        for (int i = 0; i < 4; ++i) {
            size_t off = (size_t)(n0 + wrow + 16 * i) * H_DIM + wc;
            pW1[i] = *(const int4*)&W1q[off];
            pW3[i] = *(const int4*)&W3q[off];
        }
        unsigned short* sW1 = (unsigned short*)(smem + XB);
        unsigned short* sW3 = (unsigned short*)(smem + XB + WB);
        #pragma unroll
        for (int i = 0; i < 4; ++i) {
            int row = wrow + 16 * i;
            int sidx = (n0 + row) * SG;   // gidx 0
            dq16(pW1[i], sc1[sidx], zp1[sidx], &sW1[row * LK + wc]);
            dq16(pW3[i], sc3[sidx], zp3[sidx], &sW3[row * LK + wc]);
        }
        #pragma unroll
        for (int i = 0; i < 4; ++i) {
            size_t off = (size_t)(n0 + wrow + 16 * i) * H_DIM + 64 + wc;
            pW1[i] = *(const int4*)&W1q[off];
            pW3[i] = *(const int4*)&W3q[off];
        }
    }
    __syncthreads();

    f32x4 acc[4][4];
    #pragma unroll
    for (int a = 0; a < 4; ++a)
        #pragma unroll
        for (int c = 0; c < 4; ++c) acc[a][c] = (f32x4){0.f, 0.f, 0.f, 0.f};

    constexpr int NIT = H_DIM / 64;   // 64
    #pragma unroll 2
    for (int it = 0; it < NIT; ++it) {
        const char* cb = smem + (it & 1) * BUFB;
        char* nb = smem + ((it + 1) & 1) * BUFB;

        // ---- top: issue X(it+1) DMA into the just-freed buffer ----
        if (it + 1 < NIT) {
            const int kn = (it + 1) * 64;
            #pragma unroll
            for (int j = 0; j < 4; ++j)
                gload16(xsrc + (size_t)j * 8 * H_DIM + kn,
                        nb + (wave * 4 + j) * 1024);
        }

        // ---- MFMA phase: tile `it` (X latency hides under this) ----
        const unsigned short* sX = (const unsigned short*)cb;
        const unsigned short* sB = (const unsigned short*)(cb + XB + mat * WB);
        #pragma unroll
        for (int kh = 0; kh < 2; ++kh) {
            const int kb = kh * 32 + q * 8;            // W column offset
            const int xc = (kh * 4 + q) ^ rs;          // swizzled X chunk
            bf16x8 av[4], bv[4];
            #pragma unroll
            for (int im = 0; im < 4; ++im)
                av[im] = *(const bf16x8*)&sX[(mh + im * 16 + r) * 64 + xc * 8];
            #pragma unroll
            for (int j = 0; j < 4; ++j)
                bv[j] = *(const bf16x8*)&sB[(j * 16 + r) * LK + kb];
            #pragma unroll
            for (int im = 0; im < 4; ++im)
                #pragma unroll
                for (int j = 0; j < 4; ++j)
                    acc[im][j] = __builtin_amdgcn_mfma_f32_16x16x32_bf16(av[im], bv[j], acc[im][j], 0, 0, 0);
        }

        // ---- stage: dequant pW(it+1) -> buf(it+1); pW(it+2) LATE ----
        if (it + 1 < NIT) {
            unsigned short* nW1 = (unsigned short*)(nb + XB);
            unsigned short* nW3 = (unsigned short*)(nb + XB + WB);
            const int gidx = it + 1;
            #pragma unroll
            for (int i = 0; i < 4; ++i) {
                int row = wrow + 16 * i;
                int sidx = (n0 + row) * SG + gidx;
                dq16(pW1[i], sc1[sidx], zp1[sidx], &nW1[row * LK + wc]);
                dq16(pW3[i], sc3[sidx], zp3[sidx], &nW3[row * LK + wc]);
            }
            if (it + 2 < NIT) {
                const int kf = (it + 2) * 64;
                #pragma unroll
                for (int i = 0; i < 4; ++i) {
                    size_t off = (size_t)(n0 + wrow + 16 * i) * H_DIM + kf + wc;
                    pW1[i] = *(const int4*)&W1q[off];
                    pW3[i] = *(const int4*)&W3q[off];
                }
            }
            __syncthreads();   // drains X DMA; next MFMA reads it safely
        }
    }

    // ---- epilogue: exchange g3 via LDS (buf0; final MFMA read buf1) ----
    if (mat == 1) {
        #pragma unroll
        for (int im = 0; im < 4; ++im)
            #pragma unroll
            for (int j = 0; j < 4; ++j)
                #pragma unroll
                for (int reg = 0; reg < 4; ++reg)
                    sEx[(mh + im * 16 + q * 4 + reg) * 65 + j * 16 + r] = acc[im][j][reg];
    }
    __syncthreads();
    if (mat == 0) {
        #pragma unroll
        for (int im = 0; im < 4; ++im)
            #pragma unroll
            for (int j = 0; j < 4; ++j)
                #pragma unroll
                for (int reg = 0; reg < 4; ++reg) {
                    int ml = mh + im * 16 + q * 4 + reg;
                    int nl = j * 16 + r;
                    float g1 = acc[im][j][reg];
                    float g3 = sEx[ml * 65 + nl];
                    float val = g1 / (1.f + __expf(-g1)) * g3;
                    G[(size_t)(m0 + ml) * F_DIM + n0 + nl] = f2bf(val);
                }
    }
}

// ---------------------------------------------------------------------------
// Parts[ks] = G @ W2^T over k-segment ks (plain stores; reduce_out sums).
// Tile M128 x N128 x K64, 4 waves x 64x64. Same R10 schedule: A(G) tile via
// swizzled global_load_lds issued at loop top; W2 dequant + late pW.
// LDS: 2 x (16384 A + 18432 W) = 69632 B. Grid: flat 512 = 4(m) x 32(n) x
// 4(kseg), XCD-swizzled, exactly 2 blocks/CU.
// ---------------------------------------------------------------------------
__global__ __launch_bounds__(256, 2)
void down_kernel(const unsigned short* __restrict__ G,
                 const int* __restrict__ W2q, const float* __restrict__ sc2,
                 const float* __restrict__ zp2,
                 float* __restrict__ Parts)
{
    constexpr int LK = 72;
    constexpr int AB = 128 * 64 * 2;       // 16384 B linear A tile
    constexpr int WB = 128 * LK * 2;       // 18432 B
    constexpr int BUFB = AB + WB;          // 34816 B
    __shared__ __align__(16) char smem[2 * BUFB];   // 69632 B

    const int t = threadIdx.x, wave = t >> 6, lane = t & 63;
    const int r = lane & 15, q = lane >> 4;
    const int wm = (wave & 1) * 64, wn = (wave >> 1) * 64;
    const int rs = r & 7;

    const int b = blockIdx.x;
    const int xcd = b & 7, lb = b >> 3;          // lb in [0,64)
    const int m0 = (lb & 3) * 128;
    const int pair = xcd * 16 + (lb >> 2);       // [0,128)
    const int n0 = (pair >> 2) * 128;            // 32 n-tiles
    const int ks = pair & 3;                     // k-segment
    const int kbeg = ks * (F_DIM / KSEG);
    const int SG = F_DIM / 64;

    const int wrow = t >> 4, wc = (t & 15) * 4;

    const int lrow = lane >> 3;
    const int lc   = (lane & 7) ^ lrow;
    const unsigned short* asrc =
        G + (size_t)(m0 + wave * 32 + lrow) * F_DIM + kbeg + lc * 8;

    int4 pW[8];

    // ---- prologue ----
    {
        #pragma unroll
        for (int j = 0; j < 4; ++j)
            gload16(asrc + (size_t)j * 8 * F_DIM, smem + (wave * 4 + j) * 1024);
        #pragma unroll
        for (int i = 0; i < 8; ++i)
            pW[i] = *(const int4*)&W2q[(size_t)(n0 + wrow + 16 * i) * F_DIM + kbeg + wc];
        unsigned short* sW = (unsigned short*)(smem + AB);
        const int gidx = kbeg >> 6;
        #pragma unroll
        for (int i = 0; i < 8; ++i) {
            int row = wrow + 16 * i;
            int sidx = (n0 + row) * SG + gidx;
            dq16(pW[i], sc2[sidx], zp2[sidx], &sW[row * LK + wc]);
        }
        #pragma unroll
        for (int i = 0; i < 8; ++i)
            pW[i] = *(const int4*)&W2q[(size_t)(n0 + wrow + 16 * i) * F_DIM + kbeg + 64 + wc];
    }
    __syncthreads();

    f32x4 acc[4][4];
    #pragma unroll
    for (int a = 0; a < 4; ++a)
        #pragma unroll
        for (int c = 0; c < 4; ++c) acc[a][c] = (f32x4){0.f, 0.f, 0.f, 0.f};

    constexpr int NIT = (F_DIM / KSEG) / 64;   // 56
    #pragma unroll 2
    for (int it = 0; it < NIT; ++it) {
        const char* cb = smem + (it & 1) * BUFB;
        char* nb = smem + ((it + 1) & 1) * BUFB;

        if (it + 1 < NIT) {
            const int kn = (it + 1) * 64;
            #pragma unroll
            for (int j = 0; j < 4; ++j)
                gload16(asrc + (size_t)j * 8 * F_DIM + kn,
                        nb + (wave * 4 + j) * 1024);
        }

        const unsigned short* sA = (const unsigned short*)cb;
        const unsigned short* sW = (const unsigned short*)(cb + AB);
        #pragma unroll
        for (int kh = 0; kh < 2; ++kh) {
            const int kb = kh * 32 + q * 8;
            const int xc = (kh * 4 + q) ^ rs;
            bf16x8 av[4], bv[4];
            #pragma unroll
            for (int im = 0; im < 4; ++im)
                av[im] = *(const bf16x8*)&sA[(wm + im * 16 + r) * 64 + xc * 8];
            #pragma unroll
            for (int j = 0; j < 4; ++j)
                bv[j] = *(const bf16x8*)&sW[(wn + j * 16 + r) * LK + kb];
            #pragma unroll
            for (int im = 0; im < 4; ++im)
                #pragma unroll
                for (int j = 0; j < 4; ++j)
                    acc[im][j] = __builtin_amdgcn_mfma_f32_16x16x32_bf16(av[im], bv[j], acc[im][j], 0, 0, 0);
        }

        if (it + 1 < NIT) {
            unsigned short* nW = (unsigned short*)(nb + AB);
            const int gidx = (kbeg + (it + 1) * 64) >> 6;
            #pragma unroll
            for (int i = 0; i < 8; ++i) {
                int row = wrow + 16 * i;
                int sidx = (n0 + row) * SG + gidx;
                dq16(pW[i], sc2[sidx], zp2[sidx], &nW[row * LK + wc]);
            }
            if (it + 2 < NIT) {
                const int kf = kbeg + (it + 2) * 64;
                #pragma unroll
                for (int i = 0; i < 8; ++i)
                    pW[i] = *(const int4*)&W2q[(size_t)(n0 + wrow + 16 * i) * F_DIM + kf + wc];
            }
            __syncthreads();
        }
    }

    // ---- epilogue: plain stores to this segment's partial buffer ----
    float* P = Parts + (size_t)ks * T_DIM * H_DIM;
    #pragma unroll
    for (int im = 0; im < 4; ++im)
        #pragma unroll
        for (int j = 0; j < 4; ++j)
            #pragma unroll
            for (int reg = 0; reg < 4; ++reg) {
                int m = m0 + wm + im * 16 + q * 4 + reg;
                int h = n0 + wn + j * 16 + r;
                P[(size_t)m * H_DIM + h] = acc[im][j][reg];
            }
}

extern "C" void kernel_launch(void* const* d_in, const int* in_sizes, int n_in,
                              void* d_out, int out_size, void* d_ws, size_t ws_size,
                              hipStream_t stream) {
    const float* X   = (const float*)d_in[0];
    const int*   W1q = (const int*)d_in[1];
    const float* s1  = (const float*)d_in[2];
    const float* z1  = (const float*)d_in[3];
    const int*   W3q = (const int*)d_in[4];
    const float* s3  = (const float*)d_in[5];
    const float* z3  = (const float*)d_in[6];
    const int*   W2q = (const int*)d_in[7];
    const float* s2  = (const float*)d_in[8];
    const float* z2  = (const float*)d_in[9];
    float* Out = (float*)d_out;

    unsigned short* Xb = (unsigned short*)d_ws;                        // 4 MB
    unsigned short* G  = (unsigned short*)((char*)d_ws + (4 << 20));   // 14.7 MB
    float* Parts       = (float*)((char*)d_ws + (20 << 20));           // 32 MB

    cvt_x<<<2048, 256, 0, stream>>>(X, Xb);
    gate_up_kernel<<<896, 256, 0, stream>>>(Xb, W1q, s1, z1, W3q, s3, z3, G);
    down_kernel<<<512, 256, 0, stream>>>(G, W2q, s2, z2, Parts);
    reduce_out<<<2048, 256, 0, stream>>>((const float4*)Parts, (float4*)Out);
}